// Round 2
// baseline (3003.005 us; speedup 1.0000x reference)
//
#include <hip/hip_runtime.h>
#include <math.h>

// Problem constants (from reference setup_inputs)
#define BB 16
#define DD 40
#define NN 64512
#define KK 4

#define ALPHA 5.0f
#define N_ITERS 10
#define EPS_KM 1e-9f

// ---------------------------------------------------------------------------
// Kernel 1: Vact = tanh(V), vectorized float4. B*D*N = 41287680 (div by 4).
// ---------------------------------------------------------------------------
__global__ __launch_bounds__(256) void tanh_kernel(const float4* __restrict__ V,
                                                   float4* __restrict__ Vact,
                                                   int n4) {
    int i = blockIdx.x * 256 + threadIdx.x;
    if (i < n4) {
        float4 x = V[i];
        float4 y;
        y.x = tanhf(x.x);
        y.y = tanhf(x.y);
        y.z = tanhf(x.z);
        y.w = tanhf(x.w);
        Vact[i] = y;
    }
}

// ---------------------------------------------------------------------------
// Kernel 2: init U0[b,k,d] = tanh(V[b,d,idx[b,k]]); compute u2; zero accums.
// ---------------------------------------------------------------------------
__global__ __launch_bounds__(256) void init_kernel(const float* __restrict__ V,
                                                   const int* __restrict__ idx,
                                                   float* __restrict__ U,
                                                   float* __restrict__ accV,
                                                   float* __restrict__ accS,
                                                   float* __restrict__ u2) {
    const int tid = threadIdx.x;
    for (int i = tid; i < BB * KK * DD; i += 256) {
        int b = i / (KK * DD);
        int r = i - b * (KK * DD);
        int k = r / DD;
        int d = r - k * DD;
        int n0 = idx[b * KK + k];
        U[i] = tanhf(V[(b * DD + d) * NN + n0]);
        accV[i] = 0.f;
    }
    __syncthreads();
    if (tid < BB * KK) {
        float s = 0.f;
        for (int d = 0; d < DD; ++d) {
            float x = U[tid * DD + d];
            s = fmaf(x, x, s);
        }
        u2[tid] = s;
        accS[tid] = 0.f;
    }
}

// ---------------------------------------------------------------------------
// Kernel 3: one k-means iteration — 3-phase block design.
//
// Block = 256 threads (4 waves), owns 512 consecutive n of one batch b.
// Wave w owns d-slice [10w, 10w+10). Lane l <-> n = nb + s*64 + l (all loads
// fully coalesced: 64 consecutive floats per row per instruction).
//
// Phase 1 (no barriers): 8 steps; per step load 10 rows x 64 n, compute
//   partial cross-products pc[k] and pv, write 5 partials/n to LDS
//   pp[w*5+c][n_local] (consecutive addresses -> conflict-free).
// Phase 2 (after 1 barrier): wave w softmaxes its 128-n quarter: sum the
//   4 waves' partials (consecutive reads), dist -> softmax -> y to LDS,
//   accumulate sum_y, wave-reduce, atomicAdd accS.
// Phase 3 (after 1 barrier): 8 steps; reload v (L2-hot, same coalesced
//   pattern), read y (consecutive), accumulate acc[4][10] in registers.
// Epilogue: pad-41 LDS transpose (conflict-free both directions) reduces
//   acc across the 64 lanes; 40 atomicAdds per wave into accV.
// ---------------------------------------------------------------------------
#define NPB 512            // n per block
#define GX (NN / NPB)      // 126
#define SP (NPB / 64)      // 8 steps per streaming phase

__global__ __launch_bounds__(256) void km_iter_kernel(const float* __restrict__ Vact,
                                                      const float* __restrict__ U,
                                                      const float* __restrict__ u2,
                                                      float* __restrict__ accV,
                                                      float* __restrict__ accS) {
    __shared__ float smem[20 * NPB + KK * NPB];  // 48 KB
    float (*pp)[NPB] = (float (*)[NPB])smem;             // [20][NPB] partials
    float (*yy)[NPB] = (float (*)[NPB])(smem + 20 * NPB); // [KK][NPB] y

    const int tid = threadIdx.x;
    const int w = tid >> 6;   // wave id 0..3, owns d in [10w, 10w+10)
    const int l = tid & 63;
    const int b = blockIdx.y;
    const int d0 = w * 10;
    const int nb = blockIdx.x * NPB;

    const float* Vb = Vact + (size_t)b * (size_t)(DD * NN);
    const float* Ub = U + b * (KK * DD);

    // centroid slice for this wave's d's
    float uk[KK][10];
#pragma unroll
    for (int k = 0; k < KK; ++k)
#pragma unroll
        for (int j = 0; j < 10; ++j) uk[k][j] = Ub[k * DD + d0 + j];

    int voff[10];
#pragma unroll
    for (int j = 0; j < 10; ++j) voff[j] = (d0 + j) * NN + nb + l;

    // ---------------- Phase 1: partial dot products ----------------
#pragma unroll
    for (int s = 0; s < SP; ++s) {
        float v[10];
#pragma unroll
        for (int j = 0; j < 10; ++j) v[j] = Vb[voff[j] + s * 64];

        float pv = 0.f, pc0 = 0.f, pc1 = 0.f, pc2 = 0.f, pc3 = 0.f;
#pragma unroll
        for (int j = 0; j < 10; ++j) {
            const float vv = v[j];
            pv = fmaf(vv, vv, pv);
            pc0 = fmaf(uk[0][j], vv, pc0);
            pc1 = fmaf(uk[1][j], vv, pc1);
            pc2 = fmaf(uk[2][j], vv, pc2);
            pc3 = fmaf(uk[3][j], vv, pc3);
        }
        const int nl = s * 64 + l;
        pp[w * 5 + 0][nl] = pc0;
        pp[w * 5 + 1][nl] = pc1;
        pp[w * 5 + 2][nl] = pc2;
        pp[w * 5 + 3][nl] = pc3;
        pp[w * 5 + 4][nl] = pv;
    }
    __syncthreads();

    // ---------------- Phase 2: softmax for this wave's n-quarter ----------------
    float u2r[KK];
#pragma unroll
    for (int k = 0; k < KK; ++k) u2r[k] = u2[b * KK + k];

    float sy[KK] = {0.f, 0.f, 0.f, 0.f};
#pragma unroll
    for (int s2 = 0; s2 < NPB / 256; ++s2) {  // 2 steps of 64 n
        const int nl = w * (NPB / 4) + s2 * 64 + l;
        float cc[KK];
#pragma unroll
        for (int k = 0; k < KK; ++k)
            cc[k] = pp[k][nl] + pp[5 + k][nl] + pp[10 + k][nl] + pp[15 + k][nl];
        const float v2 = pp[4][nl] + pp[9][nl] + pp[14][nl] + pp[19][nl];

        float dist[KK];
        float m = -1e30f;
#pragma unroll
        for (int k = 0; k < KK; ++k) {
            float d2 = fmaf(-2.f, cc[k], v2 + u2r[k]);
            dist[k] = -ALPHA * sqrtf(fmaxf(d2, 1e-12f));
            m = fmaxf(m, dist[k]);
        }
        float e[KK];
        float se = 0.f;
#pragma unroll
        for (int k = 0; k < KK; ++k) {
            e[k] = expf(dist[k] - m);
            se += e[k];
        }
        const float inv = 1.f / se;
#pragma unroll
        for (int k = 0; k < KK; ++k) {
            const float y = e[k] * inv;
            yy[k][nl] = y;
            sy[k] += y;
        }
    }
    // wave-reduce sum_y, one atomic per (b,k) per wave
#pragma unroll
    for (int k = 0; k < KK; ++k) {
        float sv = sy[k];
        for (int off = 32; off > 0; off >>= 1) sv += __shfl_down(sv, off, 64);
        if (l == 0) atomicAdd(&accS[b * KK + k], sv);
    }
    __syncthreads();

    // ---------------- Phase 3: accumulate y * v for this wave's d-slice ----------------
    float acc[KK][10];
#pragma unroll
    for (int k = 0; k < KK; ++k)
#pragma unroll
        for (int j = 0; j < 10; ++j) acc[k][j] = 0.f;

#pragma unroll
    for (int s = 0; s < SP; ++s) {
        float v[10];
#pragma unroll
        for (int j = 0; j < 10; ++j) v[j] = Vb[voff[j] + s * 64];
        const int nl = s * 64 + l;
        const float y0 = yy[0][nl];
        const float y1 = yy[1][nl];
        const float y2 = yy[2][nl];
        const float y3 = yy[3][nl];
#pragma unroll
        for (int j = 0; j < 10; ++j) {
            const float vv = v[j];
            acc[0][j] = fmaf(y0, vv, acc[0][j]);
            acc[1][j] = fmaf(y1, vv, acc[1][j]);
            acc[2][j] = fmaf(y2, vv, acc[2][j]);
            acc[3][j] = fmaf(y3, vv, acc[3][j]);
        }
    }
    __syncthreads();  // everyone done reading yy/pp before scratch reuse

    // ---------------- Epilogue: LDS-transpose reduce (stride 41, conflict-free) ----
    float* wr = smem + w * (64 * 41);  // wave-private region, 4*2624 <= 12288 floats
#pragma unroll
    for (int k = 0; k < KK; ++k)
#pragma unroll
        for (int j = 0; j < 10; ++j) wr[l * 41 + k * 10 + j] = acc[k][j];
    __syncthreads();

    if (l < KK * 10) {
        float s = 0.f;
        for (int l2 = 0; l2 < 64; ++l2) s += wr[l2 * 41 + l];
        const int k = l / 10;
        const int j = l - k * 10;
        atomicAdd(&accV[b * KK * DD + k * DD + d0 + j], s);
    }
}

// ---------------------------------------------------------------------------
// Kernel 4: finalize U = accV/(accS+eps); recompute u2; zero accums.
// ---------------------------------------------------------------------------
__global__ __launch_bounds__(256) void km_finalize_kernel(float* __restrict__ U,
                                                          float* __restrict__ accV,
                                                          float* __restrict__ accS,
                                                          float* __restrict__ u2) {
    const int tid = threadIdx.x;
    for (int i = tid; i < BB * KK * DD; i += 256) {
        U[i] = accV[i] / (accS[i / DD] + EPS_KM);
        accV[i] = 0.f;
    }
    __syncthreads();
    if (tid < BB * KK) {
        float s = 0.f;
        for (int d = 0; d < DD; ++d) {
            float x = U[tid * DD + d];
            s = fmaf(x, x, s);
        }
        u2[tid] = s;
        accS[tid] = 0.f;
    }
}

// ---------------------------------------------------------------------------
// Kernel 5: final mask = softmax_k( A . Vact ). grid = (252, B), 256 thr.
// ---------------------------------------------------------------------------
__global__ __launch_bounds__(256) void mask_kernel(const float* __restrict__ Vact,
                                                   const float* __restrict__ U,
                                                   float* __restrict__ mask) {
    __shared__ float sA[KK * DD];
    const int tid = threadIdx.x;
    const int b = blockIdx.y;
    const int n = blockIdx.x * 256 + tid;

    for (int i = tid; i < KK * DD; i += 256) sA[i] = U[b * KK * DD + i];
    __syncthreads();

    const float* Vb = Vact + (size_t)b * (size_t)(DD * NN);
    float d0 = 0.f, d1 = 0.f, d2 = 0.f, d3 = 0.f;
    for (int d = 0; d < DD; ++d) {
        const float vv = Vb[d * NN + n];
        d0 = fmaf(sA[0 * DD + d], vv, d0);
        d1 = fmaf(sA[1 * DD + d], vv, d1);
        d2 = fmaf(sA[2 * DD + d], vv, d2);
        d3 = fmaf(sA[3 * DD + d], vv, d3);
    }
    float m = fmaxf(fmaxf(d0, d1), fmaxf(d2, d3));
    float e0 = expf(d0 - m), e1 = expf(d1 - m), e2 = expf(d2 - m), e3 = expf(d3 - m);
    float inv = 1.f / (e0 + e1 + e2 + e3);
    float* mb = mask + (size_t)b * (size_t)(KK * NN);
    mb[0 * NN + n] = e0 * inv;
    mb[1 * NN + n] = e1 * inv;
    mb[2 * NN + n] = e2 * inv;
    mb[3 * NN + n] = e3 * inv;
}

// ---------------------------------------------------------------------------
// Kernel 6: copy A (=U after 10 iters) to the output tail.
// ---------------------------------------------------------------------------
__global__ __launch_bounds__(256) void copyA_kernel(const float* __restrict__ U,
                                                    float* __restrict__ Aout) {
    int i = blockIdx.x * 256 + threadIdx.x;
    if (i < BB * KK * DD) Aout[i] = U[i];
}

// ---------------------------------------------------------------------------
extern "C" void kernel_launch(void* const* d_in, const int* in_sizes, int n_in,
                              void* d_out, int out_size, void* d_ws, size_t ws_size,
                              hipStream_t stream) {
    const float* V = (const float*)d_in[0];
    const int* idx = (const int*)d_in[1];

    float* out = (float*)d_out;
    float* mask = out;                                   // B*K*N
    float* Vact = out + (size_t)BB * KK * NN;            // B*D*N
    float* Aout = Vact + (size_t)BB * DD * NN;           // B*K*D

    float* ws = (float*)d_ws;
    float* U    = ws;            // 2560
    float* accV = ws + 2560;     // 2560
    float* accS = ws + 5120;     // 64
    float* u2   = ws + 5184;     // 64

    const int n4 = (BB * DD * NN) / 4;  // 10321920
    tanh_kernel<<<dim3((n4 + 255) / 256), dim3(256), 0, stream>>>(
        (const float4*)V, (float4*)Vact, n4);
    init_kernel<<<dim3(1), dim3(256), 0, stream>>>(V, idx, U, accV, accS, u2);

    for (int it = 0; it < N_ITERS; ++it) {
        km_iter_kernel<<<dim3(GX, BB), dim3(256), 0, stream>>>(Vact, U, u2, accV, accS);
        km_finalize_kernel<<<dim3(1), dim3(256), 0, stream>>>(U, accV, accS, u2);
    }

    mask_kernel<<<dim3(NN / 256, BB), dim3(256), 0, stream>>>(Vact, U, mask);
    copyA_kernel<<<dim3(10), dim3(256), 0, stream>>>(U, Aout);
}